// Round 1
// 165.181 us; speedup vs baseline: 1.0310x; 1.0310x over previous
//
#include <hip/hip_runtime.h>
#include <cstdint>
#include <cstddef>

typedef unsigned short u16;
typedef unsigned int   u32;
typedef __attribute__((ext_vector_type(4))) float  f32x4;
typedef __attribute__((ext_vector_type(2))) u32    u32x2;
typedef __attribute__((ext_vector_type(8))) __bf16 bf16x8;

#define PSW   1056    // fallback: staged padded-image row width
#define ASTR  72      // fallback LDS row stride
#define CFW   4128    // Cfull row stride (elems); data cols 0..4119, zeros to 4127
#define RPAD  4128    // prep: padded row floats, coord p stored at idx p+4

// ws layout (bytes)
#define WS_BT  0u
#define WS_CF  1048576u                       // Bt: 512*1024*2
#define WS_AB  (1048576u + 16908288u)         // Cfull: 64*32*4128*2
#define WS_NEED (1048576u + 16908288u + 4194304u)  // + Abound: 64*32*512*4

static __device__ __forceinline__ float b2f(u32 u) {
  union { u32 i; float f; } c; c.i = u << 16; return c.f;
}
static __device__ __forceinline__ u16 f2b(float f) {
  union { float f; u32 i; } c; c.f = f;
  return (u16)((c.i + 0x7FFFu + ((c.i >> 16) & 1u)) >> 16);  // RNE
}

// async global->LDS DMA. LDS dest is WAVE-UNIFORM base + lane*size (m104).
static __device__ __forceinline__ void gl_lds16(const void* g, void* l) {
  __builtin_amdgcn_global_load_lds(
      (__attribute__((address_space(1))) unsigned int*)(void*)g,
      (__attribute__((address_space(3))) unsigned int*)l, 16, 0, 0);
}
static __device__ __forceinline__ void gl_lds4(const void* g, void* l) {
  __builtin_amdgcn_global_load_lds(
      (__attribute__((address_space(1))) unsigned int*)(void*)g,
      (__attribute__((address_space(3))) unsigned int*)l, 4, 0, 0);
}

// ---- standalone transpose (fallback path only)
__global__ __launch_bounds__(256) void transpose_w(const float* __restrict__ lw,
                                                   u16* __restrict__ bt) {
  __shared__ u16 tile[64][65];
  const int t  = threadIdx.x;
  const int c  = t & 63, r0 = t >> 6;
  const int n0 = blockIdx.x * 64;
  const int k0 = blockIdx.y * 64;
#pragma unroll
  for (int rr = 0; rr < 16; ++rr) {
    const int r = r0 * 16 + rr;
    tile[r][c] = f2b(lw[(size_t)(k0 + r) * 512 + n0 + c]);
  }
  __syncthreads();
#pragma unroll
  for (int rr = 0; rr < 16; ++rr) {
    const int r = r0 * 16 + rr;
    bt[(size_t)(n0 + r) * 1024 + k0 + c] = tile[c][r];
  }
}

// ---- kernel 1: fused full-image conv+bias+relu -> Cfull bf16 + boundary cols
// -> Abound.  blockIdx.y==32 rows instead transpose lin_w -> Bt (merged launch).
// Compute loop uses 4-wide output tiles so wave b128 LDS reads are lane-consecutive
// (old 16-wide tiles put all 64 lanes on banks {0..3,16..19} -> 4x serialization).
__global__ __launch_bounds__(256) void prep(
    const float* __restrict__ img, const float* __restrict__ cw,
    const float* __restrict__ cb, u16* __restrict__ cf, u32* __restrict__ ab,
    const float* __restrict__ lw, u16* __restrict__ bt)
{
  __shared__ __align__(16) float R[3][RPAD];   // 49.5 KB
  const int t = threadIdx.x;

  if (blockIdx.y == 32) {
    // ---- transpose lin_w (fp32 K=1024 x N=512) -> Bt (bf16 N=512 x K=1024)
    u16* tile = (u16*)&R[0][0];                // reuse LDS as [64][65] u16
    const int c = t & 63, r0 = t >> 6;
#pragma unroll
    for (int q = 0; q < 2; ++q) {
      const int T  = blockIdx.x * 2 + q;       // 128 tiles over 64 blocks
      const int n0 = (T & 7) << 6, k0 = (T >> 3) << 6;
      __syncthreads();
#pragma unroll
      for (int rr = 0; rr < 16; ++rr) {
        const int r = r0 * 16 + rr;
        tile[r * 65 + c] = f2b(lw[(size_t)(k0 + r) * 512 + n0 + c]);
      }
      __syncthreads();
#pragma unroll
      for (int rr = 0; rr < 16; ++rr) {
        const int r = r0 * 16 + rr;
        bt[(size_t)(n0 + r) * 1024 + k0 + c] = tile[c * 65 + r];
      }
    }
    return;
  }

  const int b = blockIdx.x, h = blockIdx.y;
  const float* imgb = img + (size_t)b * 32 * 4096;
#pragma unroll
  for (int r = 0; r < 3; ++r) {
    const int hh = h - 1 + r;
    const int live = (hh >= 0 && hh <= 31);
    const float live1 = live ? 1.0f : 0.0f;
    const float* row = imgb + (ptrdiff_t)hh * 4096;
    for (int k = t; k < 1024; k += 256) {
      f32x4 v = (f32x4)0.0f;
      if (live) v = *(const f32x4*)(row + (k << 2));
      *(f32x4*)(&R[r][16 + (k << 2)]) = v;     // padded coord p -> idx p+4; img at 16..4111
    }
    if (t < 12)      R[r][4 + t]    = live1;   // left 1.0 pad, coords 0..11
    else if (t < 24) R[r][4100 + t] = live1;   // right 1.0 pad, idx 4112..4123
    else if (t < 28) R[r][4100 + t] = 0.0f;    // zero slack idx 4124..4127
    else if (t < 32) R[r][t - 28]   = 0.0f;    // zero slack idx 0..3
  }
  __syncthreads();
  float w[9];
#pragma unroll
  for (int q = 0; q < 9; ++q) w[q] = cw[q];
  const float bias = cb[0];
  u16* dst = cf + (size_t)(b * 32 + h) * CFW;
  if (t == 0) *(uint4*)(dst + 4120) = make_uint4(0u, 0u, 0u, 0u);  // zero tail

  for (int c4 = t; c4 < 1030; c4 += 256) {     // 4 outputs per tile, lane-consecutive
    float wf[3][12];                            // idx window [4*c4, 4*c4+12)
#pragma unroll
    for (int r = 0; r < 3; ++r) {
      const f32x4* Rr = (const f32x4*)&R[r][0];
      *(f32x4*)&wf[r][0] = Rr[c4];
      *(f32x4*)&wf[r][4] = Rr[c4 + 1];
      *(f32x4*)&wf[r][8] = Rr[c4 + 2];
    }
    float o[4];
#pragma unroll
    for (int j = 0; j < 4; ++j) o[j] = bias;
#pragma unroll
    for (int r = 0; r < 3; ++r) {
      const float w0 = w[r * 3], w1 = w[r * 3 + 1], w2 = w[r * 3 + 2];
#pragma unroll
      for (int j = 0; j < 4; ++j)               // out x=4*c4+j, taps wf[j+3..j+5]
        o[j] += w0 * wf[r][j + 3] + w1 * wf[r][j + 4] + w2 * wf[r][j + 5];
    }
    u32x2 pk;
    pk.x = (u32)f2b(fmaxf(o[0], 0.f)) | ((u32)f2b(fmaxf(o[1], 0.f)) << 16);
    pk.y = (u32)f2b(fmaxf(o[2], 0.f)) | ((u32)f2b(fmaxf(o[3], 0.f)) << 16);
    *(u32x2*)(dst + (c4 << 2)) = pk;
  }

  // boundary cols j=0 / j=31 per slice (zero rows in LDS make vertical pad free)
  u32* abrow = ab + (size_t)(b * 32 + h) * 512;
#pragma unroll
  for (int ss = 0; ss < 2; ++ss) {
    const int s  = t + (ss << 8);
    const int X0 = (s << 3) + 4;               // idx of padded coord 8s
    float o0 = bias, o1 = bias;
#pragma unroll
    for (int r = 0; r < 3; ++r) {
      o0 += w[r * 3 + 1] * R[r][X0]      + w[r * 3 + 2] * R[r][X0 + 1];
      o1 += w[r * 3 + 0] * R[r][X0 + 30] + w[r * 3 + 1] * R[r][X0 + 31];
    }
    abrow[s] = (u32)f2b(fmaxf(o0, 0.f)) | ((u32)f2b(fmaxf(o1, 0.f)) << 16);
  }
}

// ---- kernel 2: GEMM (M=32768,K=1024,N=512) with global_load_lds staging.
// XCD-aware bijective swizzle: hw block i runs on XCD i%8 (m09); remap so each
// XCD owns a contiguous mt range x all 4 nt siblings -> per-XCD L2 working set
// = 2.1MB Cfull slice + 1MB Bt + 0.5MB Ab < 4MB -> DMA drains hit L2 not HBM.
__global__ __launch_bounds__(256) void gemm_k(
    const u16* __restrict__ cf, const u32* __restrict__ ab,
    const u16* __restrict__ bt, const float* __restrict__ lb,
    float* __restrict__ out)
{
  // Ps [2][1056] u16 (4224B) | Ab32 [256] u32 (1024B) | Bs 128x64 swizzled u16 (16384B)
  __shared__ __align__(16) char sm[4224 + 1024 + 16384];
  u16* Ps   = (u16*)sm;
  u32* Ab32 = (u32*)(sm + 4224);
  u16* Bs   = (u16*)(sm + 5248);
  float* Cs = (float*)sm;          // epilogue reuse [32][132]

  const int t  = threadIdx.x;
  const int orig = blockIdx.y * 4 + blockIdx.x;          // hw linear id (x-fastest)
  const int wg   = ((orig & 7) << 7) + (orig >> 3);      // bijective, 1024%8==0
  const int nt = wg & 3, mt = wg >> 2;
  const int b  = mt >> 2, s0 = (mt & 3) << 7, n0 = nt << 7;
  const int w  = t >> 6, i = t & 63;
  const int wr = w >> 1, wc = w & 1;
  const int lq = i >> 4, lr = i & 15;

  // B staging: chunk q = w*256 + j*64 + i -> n = w*32 + j*8 + (i>>3), c = (i&7)^((i>>3)&7)
  const int cB = (i & 7) ^ ((i >> 3) & 7);
  const u16* btp = bt + (size_t)(n0 + (w << 5) + (i >> 3)) * 1024 + (cB << 3);
  u16* BsW = Bs + (w << 11);                    // wave-uniform, + j*512 elems per call

  // Ps staging: chunk q = t (264 chunks; tail 256..263 by t<8)
  const int rP  = (t >= 132) ? 1 : 0;
  const int ccP = t - 132 * rP;
  const u16* cfp  = cf + (size_t)(b * 32 + rP) * CFW + (s0 << 3) + (ccP << 3);
  const u16* cfp2 = cf + (size_t)(b * 32 + 1) * CFW + (s0 << 3) + ((124 + t) << 3);
  u16* PsW = Ps + (w << 9);                     // wave-uniform

  // Ab staging: dword d = t
  const u32* abp = ab + (size_t)(b * 32 + (t >> 7)) * 512 + s0 + (t & 127);
  u32* AbW = Ab32 + (w << 6);                   // wave-uniform

  f32x4 acc[4][4];
#pragma unroll
  for (int a = 0; a < 4; ++a)
#pragma unroll
    for (int c = 0; c < 4; ++c) acc[a][c] = (f32x4)0.0f;

  for (int kk = 0; kk < 16; ++kk) {
    __syncthreads();                 // all waves done reading prev tiles
    gl_lds16(btp,              BsW);
    gl_lds16(btp +  8 * 1024,  BsW + 512);
    gl_lds16(btp + 16 * 1024,  BsW + 1024);
    gl_lds16(btp + 24 * 1024,  BsW + 1536);
    gl_lds16(cfp, PsW);
    if (t < 8) gl_lds16(cfp2, Ps + 2048);
    gl_lds4(abp, AbW);
    btp += 64; cfp += 2 * CFW; cfp2 += 2 * CFW; abp += 1024;
    __syncthreads();                 // drains vmcnt(0): DMA complete

#pragma unroll
    for (int kc = 0; kc < 2; ++kc) {
      const int bswz = (((kc << 2) + lq) ^ (lr & 7)) << 3;
      bf16x8 af[4], bfv[4];
#pragma unroll
      for (int im = 0; im < 4; ++im) {
        const int ml = wr * 64 + im * 16 + lr;
        af[im] = __builtin_bit_cast(bf16x8,
            *(const uint4*)(Ps + kc * 1056 + ((ml + lq) << 3)));
        const u32 a32 = Ab32[kc * 128 + ml];   // same addr for 4 lq -> broadcast
        union { u16 u; __bf16 h; } lo, hi;
        lo.u = (u16)(a32 & 0xffffu); hi.u = (u16)(a32 >> 16);
        if (lq == 0) af[im][0] = lo.h;         // slice col j=0
        if (lq == 3) af[im][7] = hi.h;         // slice col j=31
      }
#pragma unroll
      for (int jn = 0; jn < 4; ++jn) {
        const int n = wc * 64 + jn * 16 + lr;
        bfv[jn] = __builtin_bit_cast(bf16x8, *(const uint4*)(Bs + (n << 6) + bswz));
      }
#pragma unroll
      for (int im = 0; im < 4; ++im)
#pragma unroll
        for (int jn = 0; jn < 4; ++jn)
          acc[im][jn] = __builtin_amdgcn_mfma_f32_16x16x32_bf16(
              af[im], bfv[jn], acc[im][jn], 0, 0, 0);
    }
  }

  // epilogue: +lin_b, LDS transpose, coalesced float4 row stores
  float lbv[4];
#pragma unroll
  for (int jn = 0; jn < 4; ++jn) lbv[jn] = lb[n0 + wc * 64 + jn * 16 + lr];

  const int erow = t >> 3, ecol = (t & 7) << 4;
  const int grow_base = (mt << 7) + ((erow >> 4) * 64) + (erow & 15);

#pragma unroll
  for (int im = 0; im < 4; ++im) {
    __syncthreads();
#pragma unroll
    for (int jn = 0; jn < 4; ++jn) {
      const int cl = wc * 64 + jn * 16 + lr;
#pragma unroll
      for (int r = 0; r < 4; ++r)
        Cs[(wr * 16 + lq * 4 + r) * 132 + cl] = acc[im][jn][r] + lbv[jn];
    }
    __syncthreads();
    const size_t grow = (size_t)(grow_base + im * 16);
    float* orow = out + grow * 512 + n0 + ecol;
    const float* crow = Cs + erow * 132 + ecol;
#pragma unroll
    for (int p = 0; p < 4; ++p)
      *(f32x4*)(orow + p * 4) = *(const f32x4*)(crow + p * 4);
  }
}

// ================= fallback (round-2 fused path, needs only 1MB ws) =================
__global__ __launch_bounds__(256) void fused_fallback(
    const float* __restrict__ img, const float* __restrict__ cw,
    const float* __restrict__ cb, const u16* __restrict__ bt,
    const float* __restrict__ lb, float* __restrict__ out)
{
  __shared__ __align__(16) u16 Ps[4 * PSW];
  __shared__ __align__(16) u16 As[128 * ASTR];
  __shared__ __align__(16) u16 Bs[128 * ASTR];
  const int t = threadIdx.x, nt = blockIdx.x, mt = blockIdx.y;
  const int b = mt >> 2, s0 = (mt & 3) << 7, X0 = s0 << 3, n0 = nt << 7;
  const float* imgb = img + (size_t)b * 32 * 4096;
  float cwf[9];
#pragma unroll
  for (int q = 0; q < 9; ++q) cwf[q] = cw[q];
  const float bias = cb[0];
  const int wv = t >> 6, l = t & 63;
  const int wr = wv >> 1, wc = wv & 1, lq = l >> 4, lr = l & 15;
  const int sl = t >> 1, hsel = t & 1;
  f32x4 acc[4][4];
#pragma unroll
  for (int a = 0; a < 4; ++a)
#pragma unroll
    for (int c = 0; c < 4; ++c) acc[a][c] = (f32x4)0.0f;
  for (int kk = 0; kk < 16; ++kk) {
    const int h0 = kk << 1;
    __syncthreads();
    uint4 bsv[4];
#pragma unroll
    for (int p = 0; p < 4; ++p) {
      const int idx8 = t + (p << 8);
      const int n = idx8 >> 3, k8 = idx8 & 7;
      bsv[p] = *(const uint4*)(bt + (size_t)(n0 + n) * 1024 + (kk << 6) + (k8 << 3));
    }
    for (int idx = t; idx < 4 * PSW; idx += 256) {
      const int r = idx / PSW, xi = idx - r * PSW;
      const int h = h0 - 1 + r, x = X0 - 1 + xi;
      u16 v = 0;
      if (h >= 0 && h < 32 && x >= 0 && x < 4120)
        v = (x < 12 || x >= 4108) ? (u16)0x3F80 : f2b(imgb[h * 4096 + (x - 12)]);
      Ps[idx] = v;
    }
    __syncthreads();
    {
      const int pbase = (sl << 3);
#pragma unroll
      for (int wb = 0; wb < 32; wb += 16) {
        float o[16];
#pragma unroll
        for (int j = 0; j < 16; ++j) o[j] = bias;
#pragma unroll
        for (int dr = 0; dr < 3; ++dr) {
          const u16* p = Ps + (hsel + dr) * PSW + pbase + wb;
          const uint4 va = *(const uint4*)p;
          const uint4 vb = *(const uint4*)(p + 8);
          const u32   vc = *(const u32*)(p + 16);
          float win[18];
          win[0] = b2f(va.x & 0xffffu); win[1] = b2f(va.x >> 16);
          win[2] = b2f(va.y & 0xffffu); win[3] = b2f(va.y >> 16);
          win[4] = b2f(va.z & 0xffffu); win[5] = b2f(va.z >> 16);
          win[6] = b2f(va.w & 0xffffu); win[7] = b2f(va.w >> 16);
          win[8] = b2f(vb.x & 0xffffu); win[9] = b2f(vb.x >> 16);
          win[10] = b2f(vb.y & 0xffffu); win[11] = b2f(vb.y >> 16);
          win[12] = b2f(vb.z & 0xffffu); win[13] = b2f(vb.z >> 16);
          win[14] = b2f(vb.w & 0xffffu); win[15] = b2f(vb.w >> 16);
          win[16] = b2f(vc & 0xffffu);   win[17] = b2f(vc >> 16);
          if (wb == 0) win[0] = 0.f; else win[17] = 0.f;
          const float w0 = cwf[dr * 3], w1 = cwf[dr * 3 + 1], w2 = cwf[dr * 3 + 2];
#pragma unroll
          for (int j = 0; j < 16; ++j)
            o[j] += w0 * win[j] + w1 * win[j + 1] + w2 * win[j + 2];
        }
        u32 pk[8];
#pragma unroll
        for (int q = 0; q < 8; ++q)
          pk[q] = (u32)f2b(fmaxf(o[2 * q], 0.f)) | ((u32)f2b(fmaxf(o[2 * q + 1], 0.f)) << 16);
        uint4* dst = (uint4*)(As + sl * ASTR + (hsel << 5) + wb);
        dst[0] = make_uint4(pk[0], pk[1], pk[2], pk[3]);
        dst[1] = make_uint4(pk[4], pk[5], pk[6], pk[7]);
      }
    }
#pragma unroll
    for (int p = 0; p < 4; ++p) {
      const int idx8 = t + (p << 8);
      const int n = idx8 >> 3, k8 = idx8 & 7;
      *(uint4*)(Bs + n * ASTR + (k8 << 3)) = bsv[p];
    }
    __syncthreads();
#pragma unroll
    for (int kc = 0; kc < 2; ++kc) {
      const int ko = (kc << 5) + (lq << 3);
      bf16x8 af[4], bfv[4];
#pragma unroll
      for (int im = 0; im < 4; ++im)
        af[im] = __builtin_bit_cast(bf16x8,
            *(const uint4*)(As + (wr * 64 + im * 16 + lr) * ASTR + ko));
#pragma unroll
      for (int jn = 0; jn < 4; ++jn)
        bfv[jn] = __builtin_bit_cast(bf16x8,
            *(const uint4*)(Bs + (wc * 64 + jn * 16 + lr) * ASTR + ko));
#pragma unroll
      for (int im = 0; im < 4; ++im)
#pragma unroll
        for (int jn = 0; jn < 4; ++jn)
          acc[im][jn] = __builtin_amdgcn_mfma_f32_16x16x32_bf16(
              af[im], bfv[jn], acc[im][jn], 0, 0, 0);
    }
  }
#pragma unroll
  for (int jn = 0; jn < 4; ++jn) {
    const int col = n0 + wc * 64 + jn * 16 + lr;
    const float lbv = lb[col];
#pragma unroll
    for (int im = 0; im < 4; ++im) {
      const int row0 = (mt << 7) + wr * 64 + im * 16 + (lq << 2);
#pragma unroll
      for (int r = 0; r < 4; ++r)
        out[(size_t)(row0 + r) * 512 + col] = acc[im][jn][r] + lbv;
    }
  }
}

extern "C" void kernel_launch(void* const* d_in, const int* in_sizes, int n_in,
                              void* d_out, int out_size, void* d_ws, size_t ws_size,
                              hipStream_t stream) {
  const float* img = (const float*)d_in[0];
  const float* cw  = (const float*)d_in[1];
  const float* cb  = (const float*)d_in[2];
  const float* lw  = (const float*)d_in[3];
  const float* lb  = (const float*)d_in[4];
  float* out = (float*)d_out;

  u16* btw = (u16*)((char*)d_ws + WS_BT);

  if (ws_size >= WS_NEED) {
    u16* cfp = (u16*)((char*)d_ws + WS_CF);
    u32* abp = (u32*)((char*)d_ws + WS_AB);
    prep<<<dim3(64, 33), 256, 0, stream>>>(img, cw, cb, cfp, abp, lw, btw);
    gemm_k<<<dim3(4, 256), 256, 0, stream>>>(cfp, abp, btw, lb, out);
  } else {
    transpose_w<<<dim3(8, 16), 256, 0, stream>>>(lw, btw);
    fused_fallback<<<dim3(4, 256), 256, 0, stream>>>(img, cw, cb, btw, lb, out);
  }
}

// Round 2
// 164.417 us; speedup vs baseline: 1.0358x; 1.0047x over previous
//
#include <hip/hip_runtime.h>
#include <cstdint>
#include <cstddef>

typedef unsigned short u16;
typedef unsigned int   u32;
typedef __attribute__((ext_vector_type(4))) float  f32x4;
typedef __attribute__((ext_vector_type(2))) u32    u32x2;
typedef __attribute__((ext_vector_type(8))) __bf16 bf16x8;

#define PSW   1056    // fallback: staged padded-image row width
#define ASTR  72      // fallback LDS row stride
#define CFW   4128    // Cfull row stride (elems); data cols 0..4119, zeros to 4127
#define RPAD  4128    // prep: padded row floats, coord p stored at idx p+4
#define BUFB  21632   // gemm per-buffer LDS bytes: Ps 4224 | Ab 1024 | Bs 16384

// ws layout (bytes)
#define WS_BT  0u
#define WS_CF  1048576u                       // Bt: 512*1024*2
#define WS_AB  (1048576u + 16908288u)         // Cfull: 64*32*4128*2
#define WS_NEED (1048576u + 16908288u + 4194304u)  // + Abound: 64*32*512*4

static __device__ __forceinline__ float b2f(u32 u) {
  union { u32 i; float f; } c; c.i = u << 16; return c.f;
}
static __device__ __forceinline__ u16 f2b(float f) {
  union { float f; u32 i; } c; c.f = f;
  return (u16)((c.i + 0x7FFFu + ((c.i >> 16) & 1u)) >> 16);  // RNE
}

// async global->LDS DMA. LDS dest is WAVE-UNIFORM base + lane*size (m104).
static __device__ __forceinline__ void gl_lds16(const void* g, void* l) {
  __builtin_amdgcn_global_load_lds(
      (__attribute__((address_space(1))) unsigned int*)(void*)g,
      (__attribute__((address_space(3))) unsigned int*)l, 16, 0, 0);
}
static __device__ __forceinline__ void gl_lds4(const void* g, void* l) {
  __builtin_amdgcn_global_load_lds(
      (__attribute__((address_space(1))) unsigned int*)(void*)g,
      (__attribute__((address_space(3))) unsigned int*)l, 4, 0, 0);
}

// ---- standalone transpose (fallback path only)
__global__ __launch_bounds__(256) void transpose_w(const float* __restrict__ lw,
                                                   u16* __restrict__ bt) {
  __shared__ u16 tile[64][65];
  const int t  = threadIdx.x;
  const int c  = t & 63, r0 = t >> 6;
  const int n0 = blockIdx.x * 64;
  const int k0 = blockIdx.y * 64;
#pragma unroll
  for (int rr = 0; rr < 16; ++rr) {
    const int r = r0 * 16 + rr;
    tile[r][c] = f2b(lw[(size_t)(k0 + r) * 512 + n0 + c]);
  }
  __syncthreads();
#pragma unroll
  for (int rr = 0; rr < 16; ++rr) {
    const int r = r0 * 16 + rr;
    bt[(size_t)(n0 + r) * 1024 + k0 + c] = tile[c][r];
  }
}

// ---- kernel 1: fused full-image conv+bias+relu -> Cfull bf16 + boundary cols
// -> Abound.  Work item h==32 transposes lin_w -> Bt (merged launch).
// XCD-chunked remap: XCD x owns b in [8x,8x+8) with consecutive h adjacent in
// dispatch order -> the 3x row re-reads (h-1,h,h+1) become same-XCD L2 hits,
// and the b-range matches gemm_k's swizzle so Cfull stays L2-hot for the GEMM.
__global__ __launch_bounds__(256) void prep(
    const float* __restrict__ img, const float* __restrict__ cw,
    const float* __restrict__ cb, u16* __restrict__ cf, u32* __restrict__ ab,
    const float* __restrict__ lw, u16* __restrict__ bt)
{
  __shared__ __align__(16) float R[3][RPAD];   // 49.5 KB
  const int t = threadIdx.x;

  // hw linear id (x fastest); XCD = id%8 (m09). 2112 blocks = 8 * 264.
  const int hwid = blockIdx.y * 64 + blockIdx.x;
  const int g = (hwid & 7) * 264 + (hwid >> 3);
  const int b = g / 33, h = g - b * 33;        // h in [0,33)

  if (h == 32) {
    // ---- transpose lin_w (fp32 K=1024 x N=512) -> Bt (bf16 N=512 x K=1024)
    u16* tile = (u16*)&R[0][0];                // reuse LDS as [64][65] u16
    const int c = t & 63, r0 = t >> 6;
#pragma unroll
    for (int q = 0; q < 2; ++q) {
      const int T  = b * 2 + q;                // 128 tiles over 64 work items
      const int n0 = (T & 7) << 6, k0 = (T >> 3) << 6;
      __syncthreads();
#pragma unroll
      for (int rr = 0; rr < 16; ++rr) {
        const int r = r0 * 16 + rr;
        tile[r * 65 + c] = f2b(lw[(size_t)(k0 + r) * 512 + n0 + c]);
      }
      __syncthreads();
#pragma unroll
      for (int rr = 0; rr < 16; ++rr) {
        const int r = r0 * 16 + rr;
        bt[(size_t)(n0 + r) * 1024 + k0 + c] = tile[c * 65 + r];
      }
    }
    return;
  }

  const float* imgb = img + (size_t)b * 32 * 4096;
#pragma unroll
  for (int r = 0; r < 3; ++r) {
    const int hh = h - 1 + r;
    const int live = (hh >= 0 && hh <= 31);
    const float live1 = live ? 1.0f : 0.0f;
    const float* row = imgb + (ptrdiff_t)hh * 4096;
    for (int k = t; k < 1024; k += 256) {
      f32x4 v = (f32x4)0.0f;
      if (live) v = *(const f32x4*)(row + (k << 2));
      *(f32x4*)(&R[r][16 + (k << 2)]) = v;     // padded coord p -> idx p+4; img at 16..4111
    }
    if (t < 12)      R[r][4 + t]    = live1;   // left 1.0 pad, coords 0..11
    else if (t < 24) R[r][4100 + t] = live1;   // right 1.0 pad, idx 4112..4123
    else if (t < 28) R[r][4100 + t] = 0.0f;    // zero slack idx 4124..4127
    else if (t < 32) R[r][t - 28]   = 0.0f;    // zero slack idx 0..3
  }
  __syncthreads();
  float w[9];
#pragma unroll
  for (int q = 0; q < 9; ++q) w[q] = cw[q];
  const float bias = cb[0];
  u16* dst = cf + (size_t)(b * 32 + h) * CFW;
  if (t == 0) *(uint4*)(dst + 4120) = make_uint4(0u, 0u, 0u, 0u);  // zero tail

  for (int c4 = t; c4 < 1030; c4 += 256) {     // 4 outputs per tile, lane-consecutive
    float wf[3][12];                            // idx window [4*c4, 4*c4+12)
#pragma unroll
    for (int r = 0; r < 3; ++r) {
      const f32x4* Rr = (const f32x4*)&R[r][0];
      *(f32x4*)&wf[r][0] = Rr[c4];
      *(f32x4*)&wf[r][4] = Rr[c4 + 1];
      *(f32x4*)&wf[r][8] = Rr[c4 + 2];
    }
    float o[4];
#pragma unroll
    for (int j = 0; j < 4; ++j) o[j] = bias;
#pragma unroll
    for (int r = 0; r < 3; ++r) {
      const float w0 = w[r * 3], w1 = w[r * 3 + 1], w2 = w[r * 3 + 2];
#pragma unroll
      for (int j = 0; j < 4; ++j)               // out x=4*c4+j, taps wf[j+3..j+5]
        o[j] += w0 * wf[r][j + 3] + w1 * wf[r][j + 4] + w2 * wf[r][j + 5];
    }
    u32x2 pk;
    pk.x = (u32)f2b(fmaxf(o[0], 0.f)) | ((u32)f2b(fmaxf(o[1], 0.f)) << 16);
    pk.y = (u32)f2b(fmaxf(o[2], 0.f)) | ((u32)f2b(fmaxf(o[3], 0.f)) << 16);
    *(u32x2*)(dst + (c4 << 2)) = pk;
  }

  // boundary cols j=0 / j=31 per slice (zero rows in LDS make vertical pad free)
  u32* abrow = ab + (size_t)(b * 32 + h) * 512;
#pragma unroll
  for (int ss = 0; ss < 2; ++ss) {
    const int s  = t + (ss << 8);
    const int X0 = (s << 3) + 4;               // idx of padded coord 8s
    float o0 = bias, o1 = bias;
#pragma unroll
    for (int r = 0; r < 3; ++r) {
      o0 += w[r * 3 + 1] * R[r][X0]      + w[r * 3 + 2] * R[r][X0 + 1];
      o1 += w[r * 3 + 0] * R[r][X0 + 30] + w[r * 3 + 1] * R[r][X0 + 31];
    }
    abrow[s] = (u32)f2b(fmaxf(o0, 0.f)) | ((u32)f2b(fmaxf(o1, 0.f)) << 16);
  }
}

// ---- kernel 2: GEMM (M=32768,K=1024,N=512), 2-phase double-buffered pipeline
// (T3-minimum): STAGE(next buf) -> COMPUTE(cur buf) -> __syncthreads().
// The vmcnt(0) drain __syncthreads emits now sits AFTER compute, so next-tile
// DMA latency hides under the MFMA phase instead of sitting on the critical
// path of every K-step (round-1 postmortem: fetch fixed, time didn't move ->
// the loop was serial-latency bound, not BW bound).
__global__ __launch_bounds__(256) void gemm_k(
    const u16* __restrict__ cf, const u32* __restrict__ ab,
    const u16* __restrict__ bt, const float* __restrict__ lb,
    float* __restrict__ out)
{
  __shared__ __align__(16) char sm[2 * BUFB];   // 43.3 KB -> 3 blocks/CU
  float* Cs = (float*)sm;          // epilogue reuse [32][132]

  const int t  = threadIdx.x;
  const int orig = blockIdx.y * 4 + blockIdx.x;          // hw linear id (x-fastest)
  const int wg   = ((orig & 7) << 7) + (orig >> 3);      // bijective, 1024%8==0
  const int nt = wg & 3, mt = wg >> 2;
  const int b  = mt >> 2, s0 = (mt & 3) << 7, n0 = nt << 7;
  const int w  = t >> 6, i = t & 63;
  const int wr = w >> 1, wc = w & 1;
  const int lq = i >> 4, lr = i & 15;

  // B staging: chunk q = w*256 + j*64 + i -> n = w*32 + j*8 + (i>>3), c = (i&7)^((i>>3)&7)
  const int cB = (i & 7) ^ ((i >> 3) & 7);
  const u16* btp = bt + (size_t)(n0 + (w << 5) + (i >> 3)) * 1024 + (cB << 3);
  // Ps staging: chunk q = t (264 chunks; tail 256..263 by t<8)
  const int rP  = (t >= 132) ? 1 : 0;
  const int ccP = t - 132 * rP;
  const u16* cfp  = cf + (size_t)(b * 32 + rP) * CFW + (s0 << 3) + (ccP << 3);
  const u16* cfp2 = cf + (size_t)(b * 32 + 1) * CFW + (s0 << 3) + ((124 + t) << 3);
  // Ab staging: dword d = t
  const u32* abp = ab + (size_t)(b * 32 + (t >> 7)) * 512 + s0 + (t & 127);

  f32x4 acc[4][4];
#pragma unroll
  for (int a = 0; a < 4; ++a)
#pragma unroll
    for (int c = 0; c < 4; ++c) acc[a][c] = (f32x4)0.0f;

  auto STAGE = [&](char* base) {
    u16* PsB = (u16*)base;
    u32* AbB = (u32*)(base + 4224);
    u16* BsW = (u16*)(base + 5248) + (w << 11);   // wave-uniform
    gl_lds16(btp,              BsW);
    gl_lds16(btp +  8 * 1024,  BsW + 512);
    gl_lds16(btp + 16 * 1024,  BsW + 1024);
    gl_lds16(btp + 24 * 1024,  BsW + 1536);
    gl_lds16(cfp, PsB + (w << 9));
    if (t < 8) gl_lds16(cfp2, PsB + 2048);
    gl_lds4(abp, AbB + (w << 6));
    btp += 64; cfp += 2 * CFW; cfp2 += 2 * CFW; abp += 1024;
  };

  auto COMPUTE = [&](const char* base) {
    const u16* PsC = (const u16*)base;
    const u32* AbC = (const u32*)(base + 4224);
    const u16* BsC = (const u16*)(base + 5248);
#pragma unroll
    for (int kc = 0; kc < 2; ++kc) {
      const int bswz = (((kc << 2) + lq) ^ (lr & 7)) << 3;
      bf16x8 af[4], bfv[4];
#pragma unroll
      for (int im = 0; im < 4; ++im) {
        const int ml = wr * 64 + im * 16 + lr;
        af[im] = __builtin_bit_cast(bf16x8,
            *(const uint4*)(PsC + kc * 1056 + ((ml + lq) << 3)));
        const u32 a32 = AbC[kc * 128 + ml];    // same addr for 4 lq -> broadcast
        union { u16 u; __bf16 h; } lo, hi;
        lo.u = (u16)(a32 & 0xffffu); hi.u = (u16)(a32 >> 16);
        if (lq == 0) af[im][0] = lo.h;         // slice col j=0
        if (lq == 3) af[im][7] = hi.h;         // slice col j=31
      }
#pragma unroll
      for (int jn = 0; jn < 4; ++jn) {
        const int n = wc * 64 + jn * 16 + lr;
        bfv[jn] = __builtin_bit_cast(bf16x8, *(const uint4*)(BsC + (n << 6) + bswz));
      }
#pragma unroll
      for (int im = 0; im < 4; ++im)
#pragma unroll
        for (int jn = 0; jn < 4; ++jn)
          acc[im][jn] = __builtin_amdgcn_mfma_f32_16x16x32_bf16(
              af[im], bfv[jn], acc[im][jn], 0, 0, 0);
    }
  };

  // prologue: tile 0 into buf0
  STAGE(sm);
  __syncthreads();                      // drains vmcnt(0): tile 0 ready
#pragma unroll 1
  for (int kk = 0; kk < 14; kk += 2) {  // static buffer bases, compact code
    STAGE(sm + BUFB);                   // tile kk+1 -> buf1 (in flight over compute)
    COMPUTE(sm);                        // tile kk from buf0
    __syncthreads();                    // vmcnt(0)+barrier: tile kk+1 ready
    STAGE(sm);                          // tile kk+2 -> buf0
    COMPUTE(sm + BUFB);                 // tile kk+1
    __syncthreads();
  }
  STAGE(sm + BUFB);                     // tile 15
  COMPUTE(sm);                          // tile 14
  __syncthreads();
  COMPUTE(sm + BUFB);                   // tile 15

  // epilogue: +lin_b, LDS transpose, coalesced float4 row stores
  float lbv[4];
#pragma unroll
  for (int jn = 0; jn < 4; ++jn) lbv[jn] = lb[n0 + wc * 64 + jn * 16 + lr];

  const int erow = t >> 3, ecol = (t & 7) << 4;
  const int grow_base = (mt << 7) + ((erow >> 4) * 64) + (erow & 15);

#pragma unroll
  for (int im = 0; im < 4; ++im) {
    __syncthreads();
#pragma unroll
    for (int jn = 0; jn < 4; ++jn) {
      const int cl = wc * 64 + jn * 16 + lr;
#pragma unroll
      for (int r = 0; r < 4; ++r)
        Cs[(wr * 16 + lq * 4 + r) * 132 + cl] = acc[im][jn][r] + lbv[jn];
    }
    __syncthreads();
    const size_t grow = (size_t)(grow_base + im * 16);
    float* orow = out + grow * 512 + n0 + ecol;
    const float* crow = Cs + erow * 132 + ecol;
#pragma unroll
    for (int p = 0; p < 4; ++p)
      *(f32x4*)(orow + p * 4) = *(const f32x4*)(crow + p * 4);
  }
}

// ================= fallback (round-2 fused path, needs only 1MB ws) =================
__global__ __launch_bounds__(256) void fused_fallback(
    const float* __restrict__ img, const float* __restrict__ cw,
    const float* __restrict__ cb, const u16* __restrict__ bt,
    const float* __restrict__ lb, float* __restrict__ out)
{
  __shared__ __align__(16) u16 Ps[4 * PSW];
  __shared__ __align__(16) u16 As[128 * ASTR];
  __shared__ __align__(16) u16 Bs[128 * ASTR];
  const int t = threadIdx.x, nt = blockIdx.x, mt = blockIdx.y;
  const int b = mt >> 2, s0 = (mt & 3) << 7, X0 = s0 << 3, n0 = nt << 7;
  const float* imgb = img + (size_t)b * 32 * 4096;
  float cwf[9];
#pragma unroll
  for (int q = 0; q < 9; ++q) cwf[q] = cw[q];
  const float bias = cb[0];
  const int wv = t >> 6, l = t & 63;
  const int wr = wv >> 1, wc = wv & 1, lq = l >> 4, lr = l & 15;
  const int sl = t >> 1, hsel = t & 1;
  f32x4 acc[4][4];
#pragma unroll
  for (int a = 0; a < 4; ++a)
#pragma unroll
    for (int c = 0; c < 4; ++c) acc[a][c] = (f32x4)0.0f;
  for (int kk = 0; kk < 16; ++kk) {
    const int h0 = kk << 1;
    __syncthreads();
    uint4 bsv[4];
#pragma unroll
    for (int p = 0; p < 4; ++p) {
      const int idx8 = t + (p << 8);
      const int n = idx8 >> 3, k8 = idx8 & 7;
      bsv[p] = *(const uint4*)(bt + (size_t)(n0 + n) * 1024 + (kk << 6) + (k8 << 3));
    }
    for (int idx = t; idx < 4 * PSW; idx += 256) {
      const int r = idx / PSW, xi = idx - r * PSW;
      const int h = h0 - 1 + r, x = X0 - 1 + xi;
      u16 v = 0;
      if (h >= 0 && h < 32 && x >= 0 && x < 4120)
        v = (x < 12 || x >= 4108) ? (u16)0x3F80 : f2b(imgb[h * 4096 + (x - 12)]);
      Ps[idx] = v;
    }
    __syncthreads();
    {
      const int pbase = (sl << 3);
#pragma unroll
      for (int wb = 0; wb < 32; wb += 16) {
        float o[16];
#pragma unroll
        for (int j = 0; j < 16; ++j) o[j] = bias;
#pragma unroll
        for (int dr = 0; dr < 3; ++dr) {
          const u16* p = Ps + (hsel + dr) * PSW + pbase + wb;
          const uint4 va = *(const uint4*)p;
          const uint4 vb = *(const uint4*)(p + 8);
          const u32   vc = *(const u32*)(p + 16);
          float win[18];
          win[0] = b2f(va.x & 0xffffu); win[1] = b2f(va.x >> 16);
          win[2] = b2f(va.y & 0xffffu); win[3] = b2f(va.y >> 16);
          win[4] = b2f(va.z & 0xffffu); win[5] = b2f(va.z >> 16);
          win[6] = b2f(va.w & 0xffffu); win[7] = b2f(va.w >> 16);
          win[8] = b2f(vb.x & 0xffffu); win[9] = b2f(vb.x >> 16);
          win[10] = b2f(vb.y & 0xffffu); win[11] = b2f(vb.y >> 16);
          win[12] = b2f(vb.z & 0xffffu); win[13] = b2f(vb.z >> 16);
          win[14] = b2f(vb.w & 0xffffu); win[15] = b2f(vb.w >> 16);
          win[16] = b2f(vc & 0xffffu);   win[17] = b2f(vc >> 16);
          if (wb == 0) win[0] = 0.f; else win[17] = 0.f;
          const float w0 = cwf[dr * 3], w1 = cwf[dr * 3 + 1], w2 = cwf[dr * 3 + 2];
#pragma unroll
          for (int j = 0; j < 16; ++j)
            o[j] += w0 * win[j] + w1 * win[j + 1] + w2 * win[j + 2];
        }
        u32 pk[8];
#pragma unroll
        for (int q = 0; q < 8; ++q)
          pk[q] = (u32)f2b(fmaxf(o[2 * q], 0.f)) | ((u32)f2b(fmaxf(o[2 * q + 1], 0.f)) << 16);
        uint4* dst = (uint4*)(As + sl * ASTR + (hsel << 5) + wb);
        dst[0] = make_uint4(pk[0], pk[1], pk[2], pk[3]);
        dst[1] = make_uint4(pk[4], pk[5], pk[6], pk[7]);
      }
    }
#pragma unroll
    for (int p = 0; p < 4; ++p) {
      const int idx8 = t + (p << 8);
      const int n = idx8 >> 3, k8 = idx8 & 7;
      *(uint4*)(Bs + n * ASTR + (k8 << 3)) = bsv[p];
    }
    __syncthreads();
#pragma unroll
    for (int kc = 0; kc < 2; ++kc) {
      const int ko = (kc << 5) + (lq << 3);
      bf16x8 af[4], bfv[4];
#pragma unroll
      for (int im = 0; im < 4; ++im)
        af[im] = __builtin_bit_cast(bf16x8,
            *(const uint4*)(As + (wr * 64 + im * 16 + lr) * ASTR + ko));
#pragma unroll
      for (int jn = 0; jn < 4; ++jn)
        bfv[jn] = __builtin_bit_cast(bf16x8,
            *(const uint4*)(Bs + (wc * 64 + jn * 16 + lr) * ASTR + ko));
#pragma unroll
      for (int im = 0; im < 4; ++im)
#pragma unroll
        for (int jn = 0; jn < 4; ++jn)
          acc[im][jn] = __builtin_amdgcn_mfma_f32_16x16x32_bf16(
              af[im], bfv[jn], acc[im][jn], 0, 0, 0);
    }
  }
#pragma unroll
  for (int jn = 0; jn < 4; ++jn) {
    const int col = n0 + wc * 64 + jn * 16 + lr;
    const float lbv = lb[col];
#pragma unroll
    for (int im = 0; im < 4; ++im) {
      const int row0 = (mt << 7) + wr * 64 + im * 16 + (lq << 2);
#pragma unroll
      for (int r = 0; r < 4; ++r)
        out[(size_t)(row0 + r) * 512 + col] = acc[im][jn][r] + lbv;
    }
  }
}

extern "C" void kernel_launch(void* const* d_in, const int* in_sizes, int n_in,
                              void* d_out, int out_size, void* d_ws, size_t ws_size,
                              hipStream_t stream) {
  const float* img = (const float*)d_in[0];
  const float* cw  = (const float*)d_in[1];
  const float* cb  = (const float*)d_in[2];
  const float* lw  = (const float*)d_in[3];
  const float* lb  = (const float*)d_in[4];
  float* out = (float*)d_out;

  u16* btw = (u16*)((char*)d_ws + WS_BT);

  if (ws_size >= WS_NEED) {
    u16* cfp = (u16*)((char*)d_ws + WS_CF);
    u32* abp = (u32*)((char*)d_ws + WS_AB);
    prep<<<dim3(64, 33), 256, 0, stream>>>(img, cw, cb, cfp, abp, lw, btw);
    gemm_k<<<dim3(4, 256), 256, 0, stream>>>(cfp, abp, btw, lb, out);
  } else {
    transpose_w<<<dim3(8, 16), 256, 0, stream>>>(lw, btw);
    fused_fallback<<<dim3(4, 256), 256, 0, stream>>>(img, cw, cb, btw, lb, out);
  }
}

// Round 3
// 161.846 us; speedup vs baseline: 1.0522x; 1.0159x over previous
//
#include <hip/hip_runtime.h>
#include <cstdint>
#include <cstddef>

typedef unsigned short u16;
typedef unsigned int   u32;
typedef __attribute__((ext_vector_type(4))) float  f32x4;
typedef __attribute__((ext_vector_type(2))) float  f32x2;
typedef __attribute__((ext_vector_type(2))) u32    u32x2;
typedef __attribute__((ext_vector_type(8))) __bf16 bf16x8;

#define PSW   1056    // fallback: staged padded-image row width
#define ASTR  72      // fallback LDS row stride
#define CFW   4128    // Cfull row stride (elems); data cols 0..4119, zeros to 4127
#define WIN   2080    // prep2: staged window floats per row (coords 2048*ch-4 .. +2076)

// ws layout (bytes)
#define WS_BT  0u
#define WS_CF  1048576u                       // Bt: 512*1024*2
#define WS_AB  (1048576u + 16908288u)         // Cfull: 64*32*4128*2
#define WS_NEED (1048576u + 16908288u + 4194304u)  // + Abound: 64*32*512*4

static __device__ __forceinline__ float b2f(u32 u) {
  union { u32 i; float f; } c; c.i = u << 16; return c.f;
}
static __device__ __forceinline__ u16 f2b(float f) {
  union { float f; u32 i; } c; c.f = f;
  return (u16)((c.i + 0x7FFFu + ((c.i >> 16) & 1u)) >> 16);  // RNE
}

// async global->LDS DMA. LDS dest is WAVE-UNIFORM base + lane*size (m104).
static __device__ __forceinline__ void gl_lds16(const void* g, void* l) {
  __builtin_amdgcn_global_load_lds(
      (__attribute__((address_space(1))) unsigned int*)(void*)g,
      (__attribute__((address_space(3))) unsigned int*)l, 16, 0, 0);
}
static __device__ __forceinline__ void gl_lds4(const void* g, void* l) {
  __builtin_amdgcn_global_load_lds(
      (__attribute__((address_space(1))) unsigned int*)(void*)g,
      (__attribute__((address_space(3))) unsigned int*)l, 4, 0, 0);
}

// ---- standalone transpose (fallback path only)
__global__ __launch_bounds__(256) void transpose_w(const float* __restrict__ lw,
                                                   u16* __restrict__ bt) {
  __shared__ u16 tile[64][65];
  const int t  = threadIdx.x;
  const int c  = t & 63, r0 = t >> 6;
  const int n0 = blockIdx.x * 64;
  const int k0 = blockIdx.y * 64;
#pragma unroll
  for (int rr = 0; rr < 16; ++rr) {
    const int r = r0 * 16 + rr;
    tile[r][c] = f2b(lw[(size_t)(k0 + r) * 512 + n0 + c]);
  }
  __syncthreads();
#pragma unroll
  for (int rr = 0; rr < 16; ++rr) {
    const int r = r0 * 16 + rr;
    bt[(size_t)(n0 + r) * 1024 + k0 + c] = tile[c][r];
  }
}

// ---- kernel 1 (rewrite): streaming conv+bias+relu -> Cfull bf16 + Abound.
// 512 conv blocks = (b:64) x (col-half ch:2) x (h-quarter hq:4), 512 threads.
// 4-slot rotating LDS row ring; per h: DMA row h+2 -> compute h -> barrier.
// Image read ~1.3x total (vs 3x before), rows DMA'd via global_load_lds.
// Blocks 512..519 transpose lin_w -> Bt (merged launch).
__global__ __launch_bounds__(512) void prep2(
    const float* __restrict__ img, const float* __restrict__ cw,
    const float* __restrict__ cb, u16* __restrict__ cf, u32* __restrict__ ab,
    const float* __restrict__ lw, u16* __restrict__ bt)
{
  __shared__ __align__(16) float RING[4 * WIN];   // 33.3 KB
  const int t  = threadIdx.x;
  const int id = blockIdx.x;

  if (id >= 512) {
    // ---- transpose lin_w (fp32 K=1024 x N=512) -> Bt (bf16 N=512 x K=1024)
    u16* tile = (u16*)&RING[0];                 // reuse LDS as [64][65] u16
    const int c = t & 63, r0 = t >> 6;          // r0 in [0,8)
    for (int q = 0; q < 16; ++q) {
      const int T  = (id - 512) * 16 + q;       // 128 tiles over 8 blocks
      const int n0 = (T & 7) << 6, k0 = (T >> 3) << 6;
      __syncthreads();
#pragma unroll
      for (int rr = 0; rr < 8; ++rr) {
        const int r = r0 * 8 + rr;
        tile[r * 65 + c] = f2b(lw[(size_t)(k0 + r) * 512 + n0 + c]);
      }
      __syncthreads();
#pragma unroll
      for (int rr = 0; rr < 8; ++rr) {
        const int r = r0 * 8 + rr;
        bt[(size_t)(n0 + r) * 1024 + k0 + c] = tile[c * 65 + r];
      }
    }
    return;
  }

  const int b  = id >> 3, sub = id & 7;
  const int ch = sub & 1, hq = sub >> 1;
  const int h0 = hq << 3;
  const int col0   = ch ? 2032 : 0;   // img col of first DMA'd float
  const int wstart = ch ? 0 : 16;     // its window index
  const float* imgb = img + (size_t)b * 32 * 4096;

  float w9[9];
#pragma unroll
  for (int q = 0; q < 9; ++q) w9[q] = cw[q];
  const float bias = cb[0];

  // stage row (h0-1+i) into ring slot i&3. window idx w <-> padded coord
  // c = 2048*ch - 4 + w. Both ch: 2064 img floats = 516 chunks; <=16 edge
  // fixups disjoint from the DMA region. Dead rows (h=-1/32): all zero.
  auto STAGE = [&](int i) {
    float* sp = RING + (i & 3) * WIN;
    const int hh = h0 - 1 + i;
    if (hh >= 0 && hh <= 31) {
      const float* src = imgb + (ptrdiff_t)hh * 4096 + col0;
      gl_lds16(src + 4 * t, sp + wstart + ((t >> 6) << 8));
      if (t < 4) gl_lds16(src + 2048 + 4 * t, sp + wstart + 2048);
      if (ch == 0) { if (t < 16) sp[t] = (t < 4) ? 0.0f : 1.0f; }         // coords -4..11
      else         { if (t < 16) sp[2064 + t] = (t < 12) ? 1.0f : 0.0f; } // coords 4108..4123
    } else {
      *(f32x4*)(sp + (t << 2)) = (f32x4)0.0f;
      if (t < 8) *(f32x4*)(sp + 2048 + (t << 2)) = (f32x4)0.0f;
    }
  };

  STAGE(0); STAGE(1); STAGE(2);       // rows h0-1, h0, h0+1
  __syncthreads();                    // vmcnt(0)+lgkmcnt(0): 3 rows ready

#pragma unroll 1
  for (int it = 0; it < 8; ++it) {
    if (it < 7) STAGE(3 + it);        // row h0+2+it; slot (it+3)&3 disjoint from readers
    const int h = h0 + it;
    const float* R0 = RING + (( it      ) & 3) * WIN;  // row h-1
    const float* R1 = RING + ((it + 1) & 3) * WIN;     // row h
    const float* R2 = RING + ((it + 2) & 3) * WIN;     // row h+1
    u16* cfrow = cf + (size_t)(b * 32 + h) * CFW;

    f32x4 aa0, aa1, aa2;              // a-regs of main pass, reused for Abound
    auto CONV4 = [&](int tl, bool exp) {
      const int w4 = tl << 2;
      const f32x4 a0 = *(const f32x4*)(R0 + w4), b0 = *(const f32x4*)(R0 + w4 + 4);
      const float c0 = R0[w4 + 8];
      const f32x4 a1 = *(const f32x4*)(R1 + w4), b1 = *(const f32x4*)(R1 + w4 + 4);
      const float c1 = R1[w4 + 8];
      const f32x4 a2 = *(const f32x4*)(R2 + w4), b2 = *(const f32x4*)(R2 + w4 + 4);
      const float c2 = R2[w4 + 8];
      float o0 = bias, o1 = bias, o2 = bias, o3 = bias;
      o0 += w9[0] * a0.w + w9[1] * b0.x + w9[2] * b0.y;
      o1 += w9[0] * b0.x + w9[1] * b0.y + w9[2] * b0.z;
      o2 += w9[0] * b0.y + w9[1] * b0.z + w9[2] * b0.w;
      o3 += w9[0] * b0.z + w9[1] * b0.w + w9[2] * c0;
      o0 += w9[3] * a1.w + w9[4] * b1.x + w9[5] * b1.y;
      o1 += w9[3] * b1.x + w9[4] * b1.y + w9[5] * b1.z;
      o2 += w9[3] * b1.y + w9[4] * b1.z + w9[5] * b1.w;
      o3 += w9[3] * b1.z + w9[4] * b1.w + w9[5] * c1;
      o0 += w9[6] * a2.w + w9[7] * b2.x + w9[8] * b2.y;
      o1 += w9[6] * b2.x + w9[7] * b2.y + w9[8] * b2.z;
      o2 += w9[6] * b2.y + w9[7] * b2.z + w9[8] * b2.w;
      o3 += w9[6] * b2.z + w9[7] * b2.w + w9[8] * c2;
      u32x2 pk;
      pk.x = (u32)f2b(fmaxf(o0, 0.f)) | ((u32)f2b(fmaxf(o1, 0.f)) << 16);
      pk.y = (u32)f2b(fmaxf(o2, 0.f)) | ((u32)f2b(fmaxf(o3, 0.f)) << 16);
      *(u32x2*)(cfrow + (ch << 11) + (tl << 2)) = pk;
      if (exp) { aa0 = a0; aa1 = a1; aa2 = a2; }
    };

    CONV4(t, true);                   // outputs x = 2048*ch + 4t .. +3
    if (ch == 1) {
      if (t < 6) CONV4(512 + t, false);   // outputs 4096..4119 (right-pad region)
      if (t == 0) { u32x2 z; z.x = 0u; z.y = 0u; *(u32x2*)(cfrow + 4120) = z; }
    }

    // Abound: slice s = 256*ch + j. o0 taps w=8j+4,8j+5; o1 taps w=8j+34,8j+35.
    u16* abh = (u16*)ab + (size_t)(b * 32 + h) * 1024;
    if (t & 1) {                      // o0 for j = t>>1: w 8j+4 = 4t -> aa.x, aa.y
      const int j = t >> 1;
      float v = bias;
      v += w9[1] * aa0.x + w9[2] * aa0.y;
      v += w9[4] * aa1.x + w9[5] * aa1.y;
      v += w9[7] * aa2.x + w9[8] * aa2.y;
      abh[((ch << 8) + j) << 1] = f2b(fmaxf(v, 0.f));
    } else if (t >= 8) {              // o1 for j = (t-8)>>1: w 8j+34 = 4t+2 -> aa.z, aa.w
      const int j = (t - 8) >> 1;
      float v = bias;
      v += w9[0] * aa0.z + w9[1] * aa0.w;
      v += w9[3] * aa1.z + w9[4] * aa1.w;
      v += w9[6] * aa2.z + w9[7] * aa2.w;
      abh[(((ch << 8) + j) << 1) | 1] = f2b(fmaxf(v, 0.f));
    } else {                          // t in {0,2,4,6}: o1 for j = 252 + t/2 (right halo)
      const int j = 252 + (t >> 1);
      const int wq = 8 * j + 34;
      const f32x2 u0 = *(const f32x2*)(R0 + wq);
      const f32x2 u1 = *(const f32x2*)(R1 + wq);
      const f32x2 u2 = *(const f32x2*)(R2 + wq);
      float v = bias;
      v += w9[0] * u0.x + w9[1] * u0.y;
      v += w9[3] * u1.x + w9[4] * u1.y;
      v += w9[6] * u2.x + w9[7] * u2.y;
      abh[(((ch << 8) + j) << 1) | 1] = f2b(fmaxf(v, 0.f));
    }
    __syncthreads();                  // drains DMA(h+2); WAR fence for slot reuse
  }
}

// ---- kernel 2: GEMM (M=32768,K=1024,N=512) with global_load_lds staging.
// Round-1 proven structure (single buffer, 22KB LDS -> 7 blocks/CU capacity;
// inter-block overlap does the pipelining — r2 dbuf cut occupancy and lost 23%).
// XCD-aware bijective swizzle keeps each XCD's working set in its own L2.
__global__ __launch_bounds__(256) void gemm_k(
    const u16* __restrict__ cf, const u32* __restrict__ ab,
    const u16* __restrict__ bt, const float* __restrict__ lb,
    float* __restrict__ out)
{
  // Ps [2][1056] u16 (4224B) | Ab32 [256] u32 (1024B) | Bs 128x64 swizzled u16 (16384B)
  __shared__ __align__(16) char sm[4224 + 1024 + 16384];
  u16* Ps   = (u16*)sm;
  u32* Ab32 = (u32*)(sm + 4224);
  u16* Bs   = (u16*)(sm + 5248);
  float* Cs = (float*)sm;          // epilogue reuse [32][132]

  const int t  = threadIdx.x;
  const int orig = blockIdx.y * 4 + blockIdx.x;          // hw linear id (x-fastest)
  const int wg   = ((orig & 7) << 7) + (orig >> 3);      // bijective, 1024%8==0
  const int nt = wg & 3, mt = wg >> 2;
  const int b  = mt >> 2, s0 = (mt & 3) << 7, n0 = nt << 7;
  const int w  = t >> 6, i = t & 63;
  const int wr = w >> 1, wc = w & 1;
  const int lq = i >> 4, lr = i & 15;

  // B staging: chunk q = w*256 + j*64 + i -> n = w*32 + j*8 + (i>>3), c = (i&7)^((i>>3)&7)
  const int cB = (i & 7) ^ ((i >> 3) & 7);
  const u16* btp = bt + (size_t)(n0 + (w << 5) + (i >> 3)) * 1024 + (cB << 3);
  u16* BsW = Bs + (w << 11);                    // wave-uniform, + j*512 elems per call

  // Ps staging: chunk q = t (264 chunks; tail 256..263 by t<8)
  const int rP  = (t >= 132) ? 1 : 0;
  const int ccP = t - 132 * rP;
  const u16* cfp  = cf + (size_t)(b * 32 + rP) * CFW + (s0 << 3) + (ccP << 3);
  const u16* cfp2 = cf + (size_t)(b * 32 + 1) * CFW + (s0 << 3) + ((124 + t) << 3);
  u16* PsW = Ps + (w << 9);                     // wave-uniform

  // Ab staging: dword d = t
  const u32* abp = ab + (size_t)(b * 32 + (t >> 7)) * 512 + s0 + (t & 127);
  u32* AbW = Ab32 + (w << 6);                   // wave-uniform

  f32x4 acc[4][4];
#pragma unroll
  for (int a = 0; a < 4; ++a)
#pragma unroll
    for (int c = 0; c < 4; ++c) acc[a][c] = (f32x4)0.0f;

  for (int kk = 0; kk < 16; ++kk) {
    __syncthreads();                 // all waves done reading prev tiles
    gl_lds16(btp,              BsW);
    gl_lds16(btp +  8 * 1024,  BsW + 512);
    gl_lds16(btp + 16 * 1024,  BsW + 1024);
    gl_lds16(btp + 24 * 1024,  BsW + 1536);
    gl_lds16(cfp, PsW);
    if (t < 8) gl_lds16(cfp2, Ps + 2048);
    gl_lds4(abp, AbW);
    btp += 64; cfp += 2 * CFW; cfp2 += 2 * CFW; abp += 1024;
    __syncthreads();                 // drains vmcnt(0): DMA complete

#pragma unroll
    for (int kc = 0; kc < 2; ++kc) {
      const int bswz = (((kc << 2) + lq) ^ (lr & 7)) << 3;
      bf16x8 af[4], bfv[4];
#pragma unroll
      for (int im = 0; im < 4; ++im) {
        const int ml = wr * 64 + im * 16 + lr;
        af[im] = __builtin_bit_cast(bf16x8,
            *(const uint4*)(Ps + kc * 1056 + ((ml + lq) << 3)));
        const u32 a32 = Ab32[kc * 128 + ml];   // same addr for 4 lq -> broadcast
        union { u16 u; __bf16 h; } lo, hi;
        lo.u = (u16)(a32 & 0xffffu); hi.u = (u16)(a32 >> 16);
        if (lq == 0) af[im][0] = lo.h;         // slice col j=0
        if (lq == 3) af[im][7] = hi.h;         // slice col j=31
      }
#pragma unroll
      for (int jn = 0; jn < 4; ++jn) {
        const int n = wc * 64 + jn * 16 + lr;
        bfv[jn] = __builtin_bit_cast(bf16x8, *(const uint4*)(Bs + (n << 6) + bswz));
      }
#pragma unroll
      for (int im = 0; im < 4; ++im)
#pragma unroll
        for (int jn = 0; jn < 4; ++jn)
          acc[im][jn] = __builtin_amdgcn_mfma_f32_16x16x32_bf16(
              af[im], bfv[jn], acc[im][jn], 0, 0, 0);
    }
  }

  // epilogue: +lin_b, LDS transpose, coalesced float4 row stores
  float lbv[4];
#pragma unroll
  for (int jn = 0; jn < 4; ++jn) lbv[jn] = lb[n0 + wc * 64 + jn * 16 + lr];

  const int erow = t >> 3, ecol = (t & 7) << 4;
  const int grow_base = (mt << 7) + ((erow >> 4) * 64) + (erow & 15);

#pragma unroll
  for (int im = 0; im < 4; ++im) {
    __syncthreads();
#pragma unroll
    for (int jn = 0; jn < 4; ++jn) {
      const int cl = wc * 64 + jn * 16 + lr;
#pragma unroll
      for (int r = 0; r < 4; ++r)
        Cs[(wr * 16 + lq * 4 + r) * 132 + cl] = acc[im][jn][r] + lbv[jn];
    }
    __syncthreads();
    const size_t grow = (size_t)(grow_base + im * 16);
    float* orow = out + grow * 512 + n0 + ecol;
    const float* crow = Cs + erow * 132 + ecol;
#pragma unroll
    for (int p = 0; p < 4; ++p)
      *(f32x4*)(orow + p * 4) = *(const f32x4*)(crow + p * 4);
  }
}

// ================= fallback (round-2 fused path, needs only 1MB ws) =================
__global__ __launch_bounds__(256) void fused_fallback(
    const float* __restrict__ img, const float* __restrict__ cw,
    const float* __restrict__ cb, const u16* __restrict__ bt,
    const float* __restrict__ lb, float* __restrict__ out)
{
  __shared__ __align__(16) u16 Ps[4 * PSW];
  __shared__ __align__(16) u16 As[128 * ASTR];
  __shared__ __align__(16) u16 Bs[128 * ASTR];
  const int t = threadIdx.x, nt = blockIdx.x, mt = blockIdx.y;
  const int b = mt >> 2, s0 = (mt & 3) << 7, X0 = s0 << 3, n0 = nt << 7;
  const float* imgb = img + (size_t)b * 32 * 4096;
  float cwf[9];
#pragma unroll
  for (int q = 0; q < 9; ++q) cwf[q] = cw[q];
  const float bias = cb[0];
  const int wv = t >> 6, l = t & 63;
  const int wr = wv >> 1, wc = wv & 1, lq = l >> 4, lr = l & 15;
  const int sl = t >> 1, hsel = t & 1;
  f32x4 acc[4][4];
#pragma unroll
  for (int a = 0; a < 4; ++a)
#pragma unroll
    for (int c = 0; c < 4; ++c) acc[a][c] = (f32x4)0.0f;
  for (int kk = 0; kk < 16; ++kk) {
    const int h0 = kk << 1;
    __syncthreads();
    uint4 bsv[4];
#pragma unroll
    for (int p = 0; p < 4; ++p) {
      const int idx8 = t + (p << 8);
      const int n = idx8 >> 3, k8 = idx8 & 7;
      bsv[p] = *(const uint4*)(bt + (size_t)(n0 + n) * 1024 + (kk << 6) + (k8 << 3));
    }
    for (int idx = t; idx < 4 * PSW; idx += 256) {
      const int r = idx / PSW, xi = idx - r * PSW;
      const int h = h0 - 1 + r, x = X0 - 1 + xi;
      u16 v = 0;
      if (h >= 0 && h < 32 && x >= 0 && x < 4120)
        v = (x < 12 || x >= 4108) ? (u16)0x3F80 : f2b(imgb[h * 4096 + (x - 12)]);
      Ps[idx] = v;
    }
    __syncthreads();
    {
      const int pbase = (sl << 3);
#pragma unroll
      for (int wb = 0; wb < 32; wb += 16) {
        float o[16];
#pragma unroll
        for (int j = 0; j < 16; ++j) o[j] = bias;
#pragma unroll
        for (int dr = 0; dr < 3; ++dr) {
          const u16* p = Ps + (hsel + dr) * PSW + pbase + wb;
          const uint4 va = *(const uint4*)p;
          const uint4 vb = *(const uint4*)(p + 8);
          const u32   vc = *(const u32*)(p + 16);
          float win[18];
          win[0] = b2f(va.x & 0xffffu); win[1] = b2f(va.x >> 16);
          win[2] = b2f(va.y & 0xffffu); win[3] = b2f(va.y >> 16);
          win[4] = b2f(va.z & 0xffffu); win[5] = b2f(va.z >> 16);
          win[6] = b2f(va.w & 0xffffu); win[7] = b2f(va.w >> 16);
          win[8] = b2f(vb.x & 0xffffu); win[9] = b2f(vb.x >> 16);
          win[10] = b2f(vb.y & 0xffffu); win[11] = b2f(vb.y >> 16);
          win[12] = b2f(vb.z & 0xffffu); win[13] = b2f(vb.z >> 16);
          win[14] = b2f(vb.w & 0xffffu); win[15] = b2f(vb.w >> 16);
          win[16] = b2f(vc & 0xffffu);   win[17] = b2f(vc >> 16);
          if (wb == 0) win[0] = 0.f; else win[17] = 0.f;
          const float w0 = cwf[dr * 3], w1 = cwf[dr * 3 + 1], w2 = cwf[dr * 3 + 2];
#pragma unroll
          for (int j = 0; j < 16; ++j)
            o[j] += w0 * win[j] + w1 * win[j + 1] + w2 * win[j + 2];
        }
        u32 pk[8];
#pragma unroll
        for (int q = 0; q < 8; ++q)
          pk[q] = (u32)f2b(fmaxf(o[2 * q], 0.f)) | ((u32)f2b(fmaxf(o[2 * q + 1], 0.f)) << 16);
        uint4* dst = (uint4*)(As + sl * ASTR + (hsel << 5) + wb);
        dst[0] = make_uint4(pk[0], pk[1], pk[2], pk[3]);
        dst[1] = make_uint4(pk[4], pk[5], pk[6], pk[7]);
      }
    }
#pragma unroll
    for (int p = 0; p < 4; ++p) {
      const int idx8 = t + (p << 8);
      const int n = idx8 >> 3, k8 = idx8 & 7;
      *(uint4*)(Bs + n * ASTR + (k8 << 3)) = bsv[p];
    }
    __syncthreads();
#pragma unroll
    for (int kc = 0; kc < 2; ++kc) {
      const int ko = (kc << 5) + (lq << 3);
      bf16x8 af[4], bfv[4];
#pragma unroll
      for (int im = 0; im < 4; ++im)
        af[im] = __builtin_bit_cast(bf16x8,
            *(const uint4*)(As + (wr * 64 + im * 16 + lr) * ASTR + ko));
#pragma unroll
      for (int jn = 0; jn < 4; ++jn)
        bfv[jn] = __builtin_bit_cast(bf16x8,
            *(const uint4*)(Bs + (wc * 64 + jn * 16 + lr) * ASTR + ko));
#pragma unroll
      for (int im = 0; im < 4; ++im)
#pragma unroll
        for (int jn = 0; jn < 4; ++jn)
          acc[im][jn] = __builtin_amdgcn_mfma_f32_16x16x32_bf16(
              af[im], bfv[jn], acc[im][jn], 0, 0, 0);
    }
  }
#pragma unroll
  for (int jn = 0; jn < 4; ++jn) {
    const int col = n0 + wc * 64 + jn * 16 + lr;
    const float lbv = lb[col];
#pragma unroll
    for (int im = 0; im < 4; ++im) {
      const int row0 = (mt << 7) + wr * 64 + im * 16 + (lq << 2);
#pragma unroll
      for (int r = 0; r < 4; ++r)
        out[(size_t)(row0 + r) * 512 + col] = acc[im][jn][r] + lbv;
    }
  }
}

extern "C" void kernel_launch(void* const* d_in, const int* in_sizes, int n_in,
                              void* d_out, int out_size, void* d_ws, size_t ws_size,
                              hipStream_t stream) {
  const float* img = (const float*)d_in[0];
  const float* cw  = (const float*)d_in[1];
  const float* cb  = (const float*)d_in[2];
  const float* lw  = (const float*)d_in[3];
  const float* lb  = (const float*)d_in[4];
  float* out = (float*)d_out;

  u16* btw = (u16*)((char*)d_ws + WS_BT);

  if (ws_size >= WS_NEED) {
    u16* cfp = (u16*)((char*)d_ws + WS_CF);
    u32* abp = (u32*)((char*)d_ws + WS_AB);
    prep2<<<dim3(520), 512, 0, stream>>>(img, cw, cb, cfp, abp, lw, btw);
    gemm_k<<<dim3(4, 256), 256, 0, stream>>>(cfp, abp, btw, lb, out);
  } else {
    transpose_w<<<dim3(8, 16), 256, 0, stream>>>(lw, btw);
    fused_fallback<<<dim3(4, 256), 256, 0, stream>>>(img, cw, cb, btw, lb, out);
  }
}